// Round 5
// baseline (213.979 us; speedup 1.0000x reference)
//
#include <hip/hip_runtime.h>
#include <hip/hip_bf16.h>

typedef short s16x8 __attribute__((ext_vector_type(8)));
typedef short s16x4 __attribute__((ext_vector_type(4)));
typedef float f32x4 __attribute__((ext_vector_type(4)));
typedef __hip_bfloat16 bf16;

#define MFMA16(a, b, c) __builtin_amdgcn_mfma_f32_16x16x32_bf16((a), (b), (c), 0, 0, 0)

#define BATCH 4
#define SEQ 2048
#define NH 12
#define DH 64
#define DM 768
#define ROWS (BATCH * SEQ)       // 8192
#define QKVC (3 * DM)            // 2304
#define LOG2E 1.4426950408889634f

static __device__ inline float fast_exp2(float x) {
  float r;
  asm("v_exp_f32 %0, %1" : "=v"(r) : "v"(x));
  return r;
}
static __device__ inline unsigned pkbf16(float a, float b) {
  bf16 ha = __float2bfloat16(a), hb = __float2bfloat16(b);
  unsigned short ua, ub;
  __builtin_memcpy(&ua, &ha, 2);
  __builtin_memcpy(&ub, &hb, 2);
  return (unsigned)ua | ((unsigned)ub << 16);
}

// async global->LDS 16B copy (m97 pattern)
typedef __attribute__((address_space(3))) unsigned int lds_u32;
typedef __attribute__((address_space(1))) const unsigned int glb_u32;
static __device__ inline void gl2lds16(const void* g, void* l) {
  __builtin_amdgcn_global_load_lds((glb_u32*)g, (lds_u32*)l, 16, 0, 0);
}

// ---------------------------------------------------------------------------
// Kernel 1: fused prep with coalesced weight transposes (round-4, unchanged).
// ---------------------------------------------------------------------------
#define NTWC 432
#define NTWO 144
#define NXB  3072                  // (ROWS*DM/8)/256
__global__ __launch_bounds__(256) void prep_all(
    const float* __restrict__ wq, const float* __restrict__ wk,
    const float* __restrict__ wv, const float* __restrict__ wo,
    const float* __restrict__ x, bf16* __restrict__ WcT,
    bf16* __restrict__ WoT, bf16* __restrict__ xb) {
  __shared__ bf16 T[64 * 72];
  const int tid = threadIdx.x;
  const int blk = blockIdx.x;

  if (blk < NTWC + NTWO) {
    // -------- 64x64 transpose: dst[b][a] = src[a][b], both sides coalesced
    const float* src;
    bf16* dst;
    int sstride;
    if (blk < NTWC) {
      int mat = blk / 144, rem = blk % 144;
      int n = rem / 12, et = rem % 12;
      const float* W = (mat == 0) ? wq : ((mat == 1) ? wk : wv);
      src = W + (size_t)n * (DM * DH) + (size_t)(et * 64) * DH;  // [e][h]
      sstride = DH;
      int c0 = mat * DM + n * 64;
      dst = WcT + (size_t)c0 * DM + et * 64;                     // [h][e]
    } else {
      int t2 = blk - NTWC;
      int rt = t2 / 12, et = t2 % 12;
      src = wo + (size_t)(rt * 64) * DM + et * 64;               // [r][e]
      sstride = DM;
      dst = WoT + (size_t)(et * 64) * DM + rt * 64;              // [e][r]
    }
    for (int p = 0; p < 4; ++p) {
      int a = p * 16 + (tid >> 4);
      int b4 = (tid & 15) << 2;
      float4 v = *(const float4*)(src + (size_t)a * sstride + b4);
      T[(b4 + 0) * 72 + a] = __float2bfloat16(v.x);
      T[(b4 + 1) * 72 + a] = __float2bfloat16(v.y);
      T[(b4 + 2) * 72 + a] = __float2bfloat16(v.z);
      T[(b4 + 3) * 72 + a] = __float2bfloat16(v.w);
    }
    __syncthreads();
    for (int k = 0; k < 2; ++k) {
      int idx = tid + k * 256;
      int bb = idx >> 3, aq = (idx & 7) << 3;
      *(s16x8*)(dst + (size_t)bb * DM + aq) = *(const s16x8*)&T[bb * 72 + aq];
    }
  } else {
    // -------- x -> bf16, 8-elem chunks
    int j = (blk - NTWC - NTWO) * 256 + tid;
    const float* src = x + (size_t)j * 8;
    float4 f0 = *(const float4*)src;
    float4 f1 = *(const float4*)(src + 4);
    bf16 tmp[8];
    tmp[0] = __float2bfloat16(f0.x); tmp[1] = __float2bfloat16(f0.y);
    tmp[2] = __float2bfloat16(f0.z); tmp[3] = __float2bfloat16(f0.w);
    tmp[4] = __float2bfloat16(f1.x); tmp[5] = __float2bfloat16(f1.y);
    tmp[6] = __float2bfloat16(f1.z); tmp[7] = __float2bfloat16(f1.w);
    *(s16x8*)(xb + (size_t)j * 8) = *(const s16x8*)tmp;
  }
}

// ---------------------------------------------------------------------------
// Kernel 2: QKV projection GEMM (round-4, unchanged; 2-phase dbuf + coalesced
// V epilogue via LDS transpose).
// ---------------------------------------------------------------------------
__global__ __launch_bounds__(256) void qkv_gemm(
    const bf16* __restrict__ xb, const bf16* __restrict__ WcT,
    const float* __restrict__ bQ, const float* __restrict__ bK,
    const float* __restrict__ bV, bf16* __restrict__ Qb,
    bf16* __restrict__ Kb, bf16* __restrict__ Vt) {
  __shared__ bf16 smem[16384];  // As[2][4096] | Bs[2][4096]  (32 KB)
  bf16* As = smem;
  bf16* Bs = smem + 8192;
  const int m0 = blockIdx.x * 128;
  const int n0 = blockIdx.y * 128;
  const int tid = threadIdx.x;
  const int wave = tid >> 6, lane = tid & 63;
  const int quad = lane >> 4, l15 = lane & 15;
  const int wm = (wave & 1) * 64, wn = (wave >> 1) * 64;

  const int r0 = tid >> 2, sg0 = (tid & 3) << 3;
  const int c1 = tid + 256, r1 = c1 >> 2, sg1 = (c1 & 3) << 3;

  auto stage = [&](int k0, int buf) {
    gl2lds16(xb + (size_t)(m0 + r0) * DM + k0 + sg0, As + buf * 4096 + tid * 8);
    gl2lds16(WcT + (size_t)(n0 + r0) * DM + k0 + sg0, Bs + buf * 4096 + tid * 8);
    gl2lds16(xb + (size_t)(m0 + r1) * DM + k0 + sg1, As + buf * 4096 + c1 * 8);
    gl2lds16(WcT + (size_t)(n0 + r1) * DM + k0 + sg1, Bs + buf * 4096 + c1 * 8);
  };

  f32x4 acc[4][4] = {};

  stage(0, 0);
  __syncthreads();
  int cur = 0;
  const int NT = DM / 32;  // 24
  for (int t = 0; t < NT; ++t) {
    if (t + 1 < NT) stage((t + 1) * 32, cur ^ 1);
    s16x8 af[4], bfr[4];
    for (int i = 0; i < 4; i++)
      af[i] = *(const s16x8*)&As[cur * 4096 + (wm + i * 16 + l15) * 32 + quad * 8];
    for (int j = 0; j < 4; j++)
      bfr[j] = *(const s16x8*)&Bs[cur * 4096 + (wn + j * 16 + l15) * 32 + quad * 8];
    for (int i = 0; i < 4; i++)
      for (int j = 0; j < 4; j++)
        acc[i][j] = MFMA16(af[i], bfr[j], acc[i][j]);
    __syncthreads();
    cur ^= 1;
  }

  const int mat = n0 / DM;  // uniform per block (768 % 128 == 0)
  if (mat == 2) {
    // ---- V epilogue: transpose via LDS, coalesced Vt stores ----
    bf16* VT = smem;  // 64*136 elems = 17408 B <= 32768 B, LDS dead now
    const int bb = m0 >> 11;          // whole block in one batch
    const int s_base = m0 & 2047;
    for (int half = 0; half < 2; ++half) {
      if ((wave >> 1) == half) {
        for (int j = 0; j < 4; j++) {
          int cc = n0 - 2 * DM + wn + j * 16 + l15;
          float bsv = bV[cc];
          unsigned* row = (unsigned*)&VT[(j * 16 + l15) * 136];
          for (int i = 0; i < 4; i++) {
            int sl = wm + i * 16 + quad * 4;
            row[(sl >> 1) + 0] = pkbf16(acc[i][j][0] + bsv, acc[i][j][1] + bsv);
            row[(sl >> 1) + 1] = pkbf16(acc[i][j][2] + bsv, acc[i][j][3] + bsv);
          }
        }
      }
      __syncthreads();
      for (int k = 0; k < 4; ++k) {
        int idx = tid + k * 256;
        int cl = idx >> 4, sq = (idx & 15) << 3;
        int cc = n0 - 2 * DM + half * 64 + cl;
        int head = cc >> 6, hh = cc & 63;
        int bh = bb * NH + head;
        *(s16x8*)(Vt + ((size_t)bh * DH + hh) * SEQ + s_base + sq) =
            *(const s16x8*)&VT[cl * 136 + sq];
      }
      __syncthreads();
    }
    return;
  }

  for (int j = 0; j < 4; j++) {
    int col = n0 + wn + j * 16 + l15;
    int cc = col - mat * DM;
    int head = cc >> 6, h = cc & 63;
    float bsv = ((mat == 0) ? bQ : bK)[cc];
    for (int i = 0; i < 4; i++) {
      int row0 = m0 + wm + i * 16 + quad * 4;
      int b = row0 >> 11;
      int s = row0 & 2047;
      int bh = b * NH + head;
      const float scale = (mat == 0) ? (0.125f * LOG2E) : 1.0f;
      bf16* dst = ((mat == 0) ? Qb : Kb) + ((size_t)bh * SEQ + s) * DH + h;
      for (int r = 0; r < 4; r++)
        dst[(size_t)r * DH] = __float2bfloat16((acc[i][j][r] + bsv) * scale);
    }
  }
}

// ---------------------------------------------------------------------------
// Kernel 3: flash attention (causal), round-0 compute structure, NEW:
// K/V LDS double-buffered -> ONE barrier per k-iter (was two + serialized
// store). store(cur^1) hides under compute; loads span the whole iter.
// LDS 46080 B -> still 3 blocks/CU (grid-limited at 3 anyway).
// ---------------------------------------------------------------------------
__global__ __launch_bounds__(256) void flash_kernel(
    const bf16* __restrict__ Qb, const bf16* __restrict__ Kb,
    const bf16* __restrict__ Vt, bf16* __restrict__ Z) {
  __shared__ bf16 Ks[2][64 * 72];    // [buf][key][h], padded
  __shared__ bf16 VsT[2][64 * 72];   // [buf][h][key], padded
  __shared__ bf16 Ps[4][16 * 72];    // per-wave P [q][key], padded

  const int bh = blockIdx.x >> 4;  // 0..47
  const int p = blockIdx.x & 15;   // 0..15
  const int qtA = 31 - p, qtB = p;
  const int b = bh / NH, head = bh % NH;
  const int tid = threadIdx.x;
  const int wave = tid >> 6, lane = tid & 63;
  const int quad = lane >> 4, l15 = lane & 15;
  const int qwA = qtA * 64 + wave * 16;  // this wave's 16 q rows (tile A)
  const int qwB = qtB * 64 + wave * 16;  // tile B

  const bf16* Kbase = Kb + (size_t)bh * SEQ * DH;
  const bf16* Vbase = Vt + (size_t)bh * DH * SEQ;

  // Q as B-operand: lane n=l15 -> q=qw+l15, k -> h (pre-scaled 0.125*log2e).
  s16x8 bqA[2], bqB[2];
  for (int ks = 0; ks < 2; ks++) {
    bqA[ks] = *(const s16x8*)(Qb +
        ((size_t)bh * SEQ + qwA + l15) * DH + ks * 32 + quad * 8);
    bqB[ks] = *(const s16x8*)(Qb +
        ((size_t)bh * SEQ + qwB + l15) * DH + ks * 32 + quad * 8);
  }

  f32x4 oA[4] = {}, oB[4] = {};
  float lA = 0.f, lB = 0.f;

  // staging: 256 threads x 2 chunks (16B) per matrix
  s16x8 kr[2], vr[2];
  auto load_tile = [&](int kt) {
    const int kbase = kt * 64;
    for (int u = 0; u < 2; u++) {
      int c = tid + u * 256;
      int row = c >> 3, seg = (c & 7) << 3;
      kr[u] = *(const s16x8*)(Kbase + (size_t)(kbase + row) * DH + seg);
      vr[u] = *(const s16x8*)(Vbase + (size_t)row * SEQ + kbase + seg);
    }
  };
  auto store_tile = [&](int buf) {
    for (int u = 0; u < 2; u++) {
      int c = tid + u * 256;
      int row = c >> 3, seg = (c & 7) << 3;
      *(s16x8*)&Ks[buf][row * 72 + seg] = kr[u];
      *(s16x8*)&VsT[buf][row * 72 + seg] = vr[u];
    }
  };

  auto compute = [&](int kt, int buf, const s16x8 bq[2], f32x4 o[4],
                     float& l_i, int qw, bool diag) {
    const int kbase = kt * 64;
    // S^T[key][q]: A=K (m=key), B=Q (n=q). s[ktf]: key=kbase+ktf*16+quad*4+r,
    // q = qw + l15.
    f32x4 s[4] = {};
    for (int ks = 0; ks < 2; ks++) {
      s16x8 ak[4];
      for (int ktf = 0; ktf < 4; ktf++)
        ak[ktf] =
            *(const s16x8*)&Ks[buf][(ktf * 16 + l15) * 72 + ks * 32 + quad * 8];
      for (int ktf = 0; ktf < 4; ktf++)
        s[ktf] = MFMA16(ak[ktf], bq[ks], s[ktf]);
    }

    if (diag) {  // causal mask on the diagonal tile
      int qg = qw + l15;
      for (int ktf = 0; ktf < 4; ktf++)
        for (int r = 0; r < 4; r++) {
          int kg = kbase + ktf * 16 + quad * 4 + r;
          if (kg > qg) s[ktf][r] = -1e30f;
        }
    }

    // softmax numerator: p = exp2(s) (bounded; masked -> 0); per-lane partial l
    float rs = 0.f;
    for (int ktf = 0; ktf < 4; ktf++)
      for (int r = 0; r < 4; r++) {
        float pv = fast_exp2(s[ktf][r]);
        s[ktf][r] = pv;
        rs += pv;
      }
    l_i += rs;

    // P -> per-wave LDS in [q][key] (A-operand friendly)
    bf16* Pw = Ps[wave];
    for (int ktf = 0; ktf < 4; ktf++) {
      uint2 w;
      w.x = pkbf16(s[ktf][0], s[ktf][1]);
      w.y = pkbf16(s[ktf][2], s[ktf][3]);
      *(uint2*)&Pw[l15 * 72 + ktf * 16 + quad * 4] = w;
    }
    asm volatile("s_waitcnt lgkmcnt(0)" ::: "memory");

    // PV: o[q][h] += P[q][key] * V^T[h][key]
    for (int ks2 = 0; ks2 < 2; ks2++) {
      s16x8 ap = *(const s16x8*)&Pw[l15 * 72 + ks2 * 32 + quad * 8];
      for (int hf = 0; hf < 4; hf++) {
        s16x8 bv =
            *(const s16x8*)&VsT[buf][(hf * 16 + l15) * 72 + ks2 * 32 + quad * 8];
        o[hf] = MFMA16(ap, bv, o[hf]);
      }
    }
  };

  load_tile(0);
  store_tile(0);
  __syncthreads();  // buf0 visible
  int cur = 0;
  for (int kt = 0; kt <= qtA; kt++) {
    if (kt < qtA) load_tile(kt + 1);  // global -> regs, spans the iteration
    compute(kt, cur, bqA, oA, lA, qwA, kt == qtA);
    if (kt <= qtB) compute(kt, cur, bqB, oB, lB, qwB, kt == qtB);
    if (kt < qtA) store_tile(cur ^ 1);  // regs -> alt buffer (no readers)
    __syncthreads();  // separates reads of cur (this iter) from next write;
                      // makes cur^1 stores visible for next iter
    cur ^= 1;
  }

  // epilogue: reduce l across quads, broadcast 1/l to C/D rows, write Z
  auto epilogue = [&](f32x4 o[4], float l_i, int qw) {
    float lv = l_i;
    lv += __shfl_xor(lv, 16, 64);
    lv += __shfl_xor(lv, 32, 64);
    float linv = 1.f / lv;
    for (int r = 0; r < 4; r++) {
      float li = __shfl(linv, (lane & 48) | (quad * 4 + r), 64);
      int q = qw + quad * 4 + r;
      for (int hf = 0; hf < 4; hf++) {
        Z[((size_t)b * SEQ + q) * DM + head * DH + hf * 16 + l15] =
            __float2bfloat16(o[hf][r] * li);
      }
    }
  };
  epilogue(oA, lA, qwA);
  epilogue(oB, lB, qwB);
}

// ---------------------------------------------------------------------------
// Kernel 4: output projection. NEW tile 128x64 -> grid 64x12 = 768 blocks
// = 3.0 blocks/CU even (was 384 = 1.5/CU, half the machine idle in the tail).
// Waves: 2m x 2n, per-wave 64x32 (acc[4][2]).
// ---------------------------------------------------------------------------
__global__ __launch_bounds__(256) void out_gemm(
    const bf16* __restrict__ Z, const bf16* __restrict__ WoT,
    const float* __restrict__ bO, float* __restrict__ out) {
  __shared__ bf16 As[2][128 * 32];
  __shared__ bf16 Bs[2][64 * 32];
  const int m0 = blockIdx.x * 128;
  const int n0 = blockIdx.y * 64;
  const int tid = threadIdx.x;
  const int wave = tid >> 6, lane = tid & 63;
  const int quad = lane >> 4, l15 = lane & 15;
  const int wm = (wave & 1) * 64, wn = (wave >> 1) * 32;

  const int r0 = tid >> 2, sg0 = (tid & 3) << 3;
  const int c1 = tid + 256, r1 = c1 >> 2, sg1 = (c1 & 3) << 3;

  auto stage = [&](int k0, int buf) {
    gl2lds16(Z + (size_t)(m0 + r0) * DM + k0 + sg0, &As[buf][tid * 8]);
    gl2lds16(Z + (size_t)(m0 + r1) * DM + k0 + sg1, &As[buf][c1 * 8]);
    gl2lds16(WoT + (size_t)(n0 + r0) * DM + k0 + sg0, &Bs[buf][tid * 8]);
  };

  f32x4 acc[4][2] = {};

  stage(0, 0);
  __syncthreads();
  int cur = 0;
  const int NT = DM / 32;  // 24
  for (int t = 0; t < NT; ++t) {
    if (t + 1 < NT) stage((t + 1) * 32, cur ^ 1);
    s16x8 af[4], bfr[2];
    for (int i = 0; i < 4; i++)
      af[i] = *(const s16x8*)&As[cur][(wm + i * 16 + l15) * 32 + quad * 8];
    for (int j = 0; j < 2; j++)
      bfr[j] = *(const s16x8*)&Bs[cur][(wn + j * 16 + l15) * 32 + quad * 8];
    for (int i = 0; i < 4; i++)
      for (int j = 0; j < 2; j++)
        acc[i][j] = MFMA16(af[i], bfr[j], acc[i][j]);
    __syncthreads();
    cur ^= 1;
  }

  for (int j = 0; j < 2; j++) {
    int col = n0 + wn + j * 16 + l15;
    float bv = bO[col];
    for (int i = 0; i < 4; i++)
      for (int r = 0; r < 4; r++) {
        int row = m0 + wm + i * 16 + quad * 4 + r;
        out[(size_t)row * DM + col] = acc[i][j][r] + bv;
      }
  }
}

// ---------------------------------------------------------------------------
extern "C" void kernel_launch(void* const* d_in, const int* in_sizes, int n_in,
                              void* d_out, int out_size, void* d_ws,
                              size_t ws_size, hipStream_t stream) {
  const float* x  = (const float*)d_in[0];
  const float* wq = (const float*)d_in[1];
  const float* wk = (const float*)d_in[2];
  const float* wv = (const float*)d_in[3];
  const float* wo = (const float*)d_in[4];
  const float* bq = (const float*)d_in[5];
  const float* bk = (const float*)d_in[6];
  const float* bv = (const float*)d_in[7];
  const float* bo = (const float*)d_in[8];
  float* out = (float*)d_out;

  bf16* WcT = (bf16*)d_ws;                    // 2304*768
  bf16* WoT = WcT + (size_t)QKVC * DM;        //  768*768
  bf16* Qb  = WoT + (size_t)DM * DM;          // 8192*768
  bf16* Kb  = Qb + (size_t)ROWS * DM;         // 8192*768
  bf16* Vt  = Kb + (size_t)ROWS * DM;         // 8192*768 ([bh][h][s])
  bf16* xbZ = Vt + (size_t)ROWS * DM;         // 8192*768 (xb, then Z)

  prep_all<<<NTWC + NTWO + NXB, 256, 0, stream>>>(
      wq, wk, wv, wo, x, WcT, WoT, xbZ);
  qkv_gemm<<<dim3(ROWS / 128, QKVC / 128), 256, 0, stream>>>(
      xbZ, WcT, bq, bk, bv, Qb, Kb, Vt);
  flash_kernel<<<48 * 16, 256, 0, stream>>>(Qb, Kb, Vt, xbZ);
  out_gemm<<<dim3(ROWS / 128, DM / 64), 256, 0, stream>>>(xbZ, WoT, bo, out);
}

// Round 6
// 208.007 us; speedup vs baseline: 1.0287x; 1.0287x over previous
//
#include <hip/hip_runtime.h>
#include <hip/hip_bf16.h>

typedef short s16x8 __attribute__((ext_vector_type(8)));
typedef short s16x4 __attribute__((ext_vector_type(4)));
typedef float f32x4 __attribute__((ext_vector_type(4)));
typedef __hip_bfloat16 bf16;

#define MFMA16(a, b, c) __builtin_amdgcn_mfma_f32_16x16x32_bf16((a), (b), (c), 0, 0, 0)

#define BATCH 4
#define SEQ 2048
#define NH 12
#define DH 64
#define DM 768
#define ROWS (BATCH * SEQ)       // 8192
#define QKVC (3 * DM)            // 2304
#define LOG2E 1.4426950408889634f

static __device__ inline float fast_exp2(float x) {
  float r;
  asm("v_exp_f32 %0, %1" : "=v"(r) : "v"(x));
  return r;
}
static __device__ inline unsigned pkbf16(float a, float b) {
  bf16 ha = __float2bfloat16(a), hb = __float2bfloat16(b);
  unsigned short ua, ub;
  __builtin_memcpy(&ua, &ha, 2);
  __builtin_memcpy(&ub, &hb, 2);
  return (unsigned)ua | ((unsigned)ub << 16);
}

// async global->LDS 16B copy (m97 pattern)
typedef __attribute__((address_space(3))) unsigned int lds_u32;
typedef __attribute__((address_space(1))) const unsigned int glb_u32;
static __device__ inline void gl2lds16(const void* g, void* l) {
  __builtin_amdgcn_global_load_lds((glb_u32*)g, (lds_u32*)l, 16, 0, 0);
}

// ---------------------------------------------------------------------------
// Kernel 1: fused prep with coalesced weight transposes (round-4, unchanged).
// ---------------------------------------------------------------------------
#define NTWC 432
#define NTWO 144
#define NXB  3072                  // (ROWS*DM/8)/256
__global__ __launch_bounds__(256) void prep_all(
    const float* __restrict__ wq, const float* __restrict__ wk,
    const float* __restrict__ wv, const float* __restrict__ wo,
    const float* __restrict__ x, bf16* __restrict__ WcT,
    bf16* __restrict__ WoT, bf16* __restrict__ xb) {
  __shared__ bf16 T[64 * 72];
  const int tid = threadIdx.x;
  const int blk = blockIdx.x;

  if (blk < NTWC + NTWO) {
    // -------- 64x64 transpose: dst[b][a] = src[a][b], both sides coalesced
    const float* src;
    bf16* dst;
    int sstride;
    if (blk < NTWC) {
      int mat = blk / 144, rem = blk % 144;
      int n = rem / 12, et = rem % 12;
      const float* W = (mat == 0) ? wq : ((mat == 1) ? wk : wv);
      src = W + (size_t)n * (DM * DH) + (size_t)(et * 64) * DH;  // [e][h]
      sstride = DH;
      int c0 = mat * DM + n * 64;
      dst = WcT + (size_t)c0 * DM + et * 64;                     // [h][e]
    } else {
      int t2 = blk - NTWC;
      int rt = t2 / 12, et = t2 % 12;
      src = wo + (size_t)(rt * 64) * DM + et * 64;               // [r][e]
      sstride = DM;
      dst = WoT + (size_t)(et * 64) * DM + rt * 64;              // [e][r]
    }
    for (int p = 0; p < 4; ++p) {
      int a = p * 16 + (tid >> 4);
      int b4 = (tid & 15) << 2;
      float4 v = *(const float4*)(src + (size_t)a * sstride + b4);
      T[(b4 + 0) * 72 + a] = __float2bfloat16(v.x);
      T[(b4 + 1) * 72 + a] = __float2bfloat16(v.y);
      T[(b4 + 2) * 72 + a] = __float2bfloat16(v.z);
      T[(b4 + 3) * 72 + a] = __float2bfloat16(v.w);
    }
    __syncthreads();
    for (int k = 0; k < 2; ++k) {
      int idx = tid + k * 256;
      int bb = idx >> 3, aq = (idx & 7) << 3;
      *(s16x8*)(dst + (size_t)bb * DM + aq) = *(const s16x8*)&T[bb * 72 + aq];
    }
  } else {
    // -------- x -> bf16, 8-elem chunks
    int j = (blk - NTWC - NTWO) * 256 + tid;
    const float* src = x + (size_t)j * 8;
    float4 f0 = *(const float4*)src;
    float4 f1 = *(const float4*)(src + 4);
    bf16 tmp[8];
    tmp[0] = __float2bfloat16(f0.x); tmp[1] = __float2bfloat16(f0.y);
    tmp[2] = __float2bfloat16(f0.z); tmp[3] = __float2bfloat16(f0.w);
    tmp[4] = __float2bfloat16(f1.x); tmp[5] = __float2bfloat16(f1.y);
    tmp[6] = __float2bfloat16(f1.z); tmp[7] = __float2bfloat16(f1.w);
    *(s16x8*)(xb + (size_t)j * 8) = *(const s16x8*)tmp;
  }
}

// ---------------------------------------------------------------------------
// Kernel 2: QKV projection GEMM. NEW: ring-of-3 LDS staging with COUNTED
// vmcnt (T4): loads for tile t+1 stay in flight across the barrier; only
// tile t's 4 loads are waited (vmcnt(4)). Raw s_barrier (no implicit
// vmcnt(0) drain). 48 KB LDS -> 3 blocks/CU.
// ---------------------------------------------------------------------------
__global__ __launch_bounds__(256) void qkv_gemm(
    const bf16* __restrict__ xb, const bf16* __restrict__ WcT,
    const float* __restrict__ bQ, const float* __restrict__ bK,
    const float* __restrict__ bV, bf16* __restrict__ Qb,
    bf16* __restrict__ Kb, bf16* __restrict__ Vt) {
  __shared__ bf16 smem[24576];  // As[3][4096] | Bs[3][4096]  (48 KB)
  bf16* As = smem;
  bf16* Bs = smem + 12288;
  const int m0 = blockIdx.x * 128;
  const int n0 = blockIdx.y * 128;
  const int tid = threadIdx.x;
  const int wave = tid >> 6, lane = tid & 63;
  const int quad = lane >> 4, l15 = lane & 15;
  const int wm = (wave & 1) * 64, wn = (wave >> 1) * 64;

  const int r0 = tid >> 2, sg0 = (tid & 3) << 3;
  const int c1 = tid + 256, r1 = c1 >> 2, sg1 = (c1 & 3) << 3;

  auto stage = [&](int k0, int buf) {
    gl2lds16(xb + (size_t)(m0 + r0) * DM + k0 + sg0, As + buf * 4096 + tid * 8);
    gl2lds16(WcT + (size_t)(n0 + r0) * DM + k0 + sg0, Bs + buf * 4096 + tid * 8);
    gl2lds16(xb + (size_t)(m0 + r1) * DM + k0 + sg1, As + buf * 4096 + c1 * 8);
    gl2lds16(WcT + (size_t)(n0 + r1) * DM + k0 + sg1, Bs + buf * 4096 + c1 * 8);
  };

  f32x4 acc[4][4] = {};

  stage(0, 0);   // 4 vmem ops in flight
  stage(32, 1);  // 8 in flight
  int cur = 0;
  const int NT = DM / 32;  // 24
  for (int t = 0; t < NT; ++t) {
    // tile t's loads done; tile t+1's (if issued) remain in flight
    if (t + 1 < NT) asm volatile("s_waitcnt vmcnt(4)" ::: "memory");
    else            asm volatile("s_waitcnt vmcnt(0)" ::: "memory");
    __builtin_amdgcn_s_barrier();      // all waves: tile t resident,
    asm volatile("" ::: "memory");     // iter t-1 reads complete (fence)
    if (t + 2 < NT) {
      int nxt = cur + 2; if (nxt >= 3) nxt -= 3;
      stage((t + 2) * 32, nxt);        // overwrites buf of t-1 (safe)
    }
    s16x8 af[4], bfr[4];
    for (int i = 0; i < 4; i++)
      af[i] = *(const s16x8*)&As[cur * 4096 + (wm + i * 16 + l15) * 32 + quad * 8];
    for (int j = 0; j < 4; j++)
      bfr[j] = *(const s16x8*)&Bs[cur * 4096 + (wn + j * 16 + l15) * 32 + quad * 8];
    for (int i = 0; i < 4; i++)
      for (int j = 0; j < 4; j++)
        acc[i][j] = MFMA16(af[i], bfr[j], acc[i][j]);
    cur = (cur == 2) ? 0 : cur + 1;
  }
  __syncthreads();  // all waves done with smem before V-epilogue reuse

  const int mat = n0 / DM;  // uniform per block (768 % 128 == 0)
  if (mat == 2) {
    // ---- V epilogue: transpose via LDS, coalesced Vt stores ----
    bf16* VT = smem;  // 64*136 elems = 17408 B, LDS dead now
    const int bb = m0 >> 11;          // whole block in one batch
    const int s_base = m0 & 2047;
    for (int half = 0; half < 2; ++half) {
      if ((wave >> 1) == half) {
        for (int j = 0; j < 4; j++) {
          int cc = n0 - 2 * DM + wn + j * 16 + l15;
          float bsv = bV[cc];
          unsigned* row = (unsigned*)&VT[(j * 16 + l15) * 136];
          for (int i = 0; i < 4; i++) {
            int sl = wm + i * 16 + quad * 4;
            row[(sl >> 1) + 0] = pkbf16(acc[i][j][0] + bsv, acc[i][j][1] + bsv);
            row[(sl >> 1) + 1] = pkbf16(acc[i][j][2] + bsv, acc[i][j][3] + bsv);
          }
        }
      }
      __syncthreads();
      for (int k = 0; k < 4; ++k) {
        int idx = tid + k * 256;
        int cl = idx >> 4, sq = (idx & 15) << 3;
        int cc = n0 - 2 * DM + half * 64 + cl;
        int head = cc >> 6, hh = cc & 63;
        int bh = bb * NH + head;
        *(s16x8*)(Vt + ((size_t)bh * DH + hh) * SEQ + s_base + sq) =
            *(const s16x8*)&VT[cl * 136 + sq];
      }
      __syncthreads();
    }
    return;
  }

  for (int j = 0; j < 4; j++) {
    int col = n0 + wn + j * 16 + l15;
    int cc = col - mat * DM;
    int head = cc >> 6, h = cc & 63;
    float bsv = ((mat == 0) ? bQ : bK)[cc];
    for (int i = 0; i < 4; i++) {
      int row0 = m0 + wm + i * 16 + quad * 4;
      int b = row0 >> 11;
      int s = row0 & 2047;
      int bh = b * NH + head;
      const float scale = (mat == 0) ? (0.125f * LOG2E) : 1.0f;
      bf16* dst = ((mat == 0) ? Qb : Kb) + ((size_t)bh * SEQ + s) * DH + h;
      for (int r = 0; r < 4; r++)
        dst[(size_t)r * DH] = __float2bfloat16((acc[i][j][r] + bsv) * scale);
    }
  }
}

// ---------------------------------------------------------------------------
// Kernel 3: flash attention (causal) — round-5 config, UNCHANGED (control).
// K/V LDS double-buffered, one barrier per k-iter. 59 us measured.
// ---------------------------------------------------------------------------
__global__ __launch_bounds__(256) void flash_kernel(
    const bf16* __restrict__ Qb, const bf16* __restrict__ Kb,
    const bf16* __restrict__ Vt, bf16* __restrict__ Z) {
  __shared__ bf16 Ks[2][64 * 72];    // [buf][key][h], padded
  __shared__ bf16 VsT[2][64 * 72];   // [buf][h][key], padded
  __shared__ bf16 Ps[4][16 * 72];    // per-wave P [q][key], padded

  const int bh = blockIdx.x >> 4;  // 0..47
  const int p = blockIdx.x & 15;   // 0..15
  const int qtA = 31 - p, qtB = p;
  const int b = bh / NH, head = bh % NH;
  const int tid = threadIdx.x;
  const int wave = tid >> 6, lane = tid & 63;
  const int quad = lane >> 4, l15 = lane & 15;
  const int qwA = qtA * 64 + wave * 16;  // this wave's 16 q rows (tile A)
  const int qwB = qtB * 64 + wave * 16;  // tile B

  const bf16* Kbase = Kb + (size_t)bh * SEQ * DH;
  const bf16* Vbase = Vt + (size_t)bh * DH * SEQ;

  // Q as B-operand: lane n=l15 -> q=qw+l15, k -> h (pre-scaled 0.125*log2e).
  s16x8 bqA[2], bqB[2];
  for (int ks = 0; ks < 2; ks++) {
    bqA[ks] = *(const s16x8*)(Qb +
        ((size_t)bh * SEQ + qwA + l15) * DH + ks * 32 + quad * 8);
    bqB[ks] = *(const s16x8*)(Qb +
        ((size_t)bh * SEQ + qwB + l15) * DH + ks * 32 + quad * 8);
  }

  f32x4 oA[4] = {}, oB[4] = {};
  float lA = 0.f, lB = 0.f;

  // staging: 256 threads x 2 chunks (16B) per matrix
  s16x8 kr[2], vr[2];
  auto load_tile = [&](int kt) {
    const int kbase = kt * 64;
    for (int u = 0; u < 2; u++) {
      int c = tid + u * 256;
      int row = c >> 3, seg = (c & 7) << 3;
      kr[u] = *(const s16x8*)(Kbase + (size_t)(kbase + row) * DH + seg);
      vr[u] = *(const s16x8*)(Vbase + (size_t)row * SEQ + kbase + seg);
    }
  };
  auto store_tile = [&](int buf) {
    for (int u = 0; u < 2; u++) {
      int c = tid + u * 256;
      int row = c >> 3, seg = (c & 7) << 3;
      *(s16x8*)&Ks[buf][row * 72 + seg] = kr[u];
      *(s16x8*)&VsT[buf][row * 72 + seg] = vr[u];
    }
  };

  auto compute = [&](int kt, int buf, const s16x8 bq[2], f32x4 o[4],
                     float& l_i, int qw, bool diag) {
    const int kbase = kt * 64;
    // S^T[key][q]: A=K (m=key), B=Q (n=q). s[ktf]: key=kbase+ktf*16+quad*4+r,
    // q = qw + l15.
    f32x4 s[4] = {};
    for (int ks = 0; ks < 2; ks++) {
      s16x8 ak[4];
      for (int ktf = 0; ktf < 4; ktf++)
        ak[ktf] =
            *(const s16x8*)&Ks[buf][(ktf * 16 + l15) * 72 + ks * 32 + quad * 8];
      for (int ktf = 0; ktf < 4; ktf++)
        s[ktf] = MFMA16(ak[ktf], bq[ks], s[ktf]);
    }

    if (diag) {  // causal mask on the diagonal tile
      int qg = qw + l15;
      for (int ktf = 0; ktf < 4; ktf++)
        for (int r = 0; r < 4; r++) {
          int kg = kbase + ktf * 16 + quad * 4 + r;
          if (kg > qg) s[ktf][r] = -1e30f;
        }
    }

    // softmax numerator: p = exp2(s) (bounded; masked -> 0); per-lane partial l
    float rs = 0.f;
    for (int ktf = 0; ktf < 4; ktf++)
      for (int r = 0; r < 4; r++) {
        float pv = fast_exp2(s[ktf][r]);
        s[ktf][r] = pv;
        rs += pv;
      }
    l_i += rs;

    // P -> per-wave LDS in [q][key] (A-operand friendly)
    bf16* Pw = Ps[wave];
    for (int ktf = 0; ktf < 4; ktf++) {
      uint2 w;
      w.x = pkbf16(s[ktf][0], s[ktf][1]);
      w.y = pkbf16(s[ktf][2], s[ktf][3]);
      *(uint2*)&Pw[l15 * 72 + ktf * 16 + quad * 4] = w;
    }
    asm volatile("s_waitcnt lgkmcnt(0)" ::: "memory");

    // PV: o[q][h] += P[q][key] * V^T[h][key]
    for (int ks2 = 0; ks2 < 2; ks2++) {
      s16x8 ap = *(const s16x8*)&Pw[l15 * 72 + ks2 * 32 + quad * 8];
      for (int hf = 0; hf < 4; hf++) {
        s16x8 bv =
            *(const s16x8*)&VsT[buf][(hf * 16 + l15) * 72 + ks2 * 32 + quad * 8];
        o[hf] = MFMA16(ap, bv, o[hf]);
      }
    }
  };

  load_tile(0);
  store_tile(0);
  __syncthreads();  // buf0 visible
  int cur = 0;
  for (int kt = 0; kt <= qtA; kt++) {
    if (kt < qtA) load_tile(kt + 1);  // global -> regs, spans the iteration
    compute(kt, cur, bqA, oA, lA, qwA, kt == qtA);
    if (kt <= qtB) compute(kt, cur, bqB, oB, lB, qwB, kt == qtB);
    if (kt < qtA) store_tile(cur ^ 1);  // regs -> alt buffer (no readers)
    __syncthreads();  // separates reads of cur (this iter) from next write;
                      // makes cur^1 stores visible for next iter
    cur ^= 1;
  }

  // epilogue: reduce l across quads, broadcast 1/l to C/D rows, write Z
  auto epilogue = [&](f32x4 o[4], float l_i, int qw) {
    float lv = l_i;
    lv += __shfl_xor(lv, 16, 64);
    lv += __shfl_xor(lv, 32, 64);
    float linv = 1.f / lv;
    for (int r = 0; r < 4; r++) {
      float li = __shfl(linv, (lane & 48) | (quad * 4 + r), 64);
      int q = qw + quad * 4 + r;
      for (int hf = 0; hf < 4; hf++) {
        Z[((size_t)b * SEQ + q) * DM + head * DH + hf * 16 + l15] =
            __float2bfloat16(o[hf][r] * li);
      }
    }
  };
  epilogue(oA, lA, qwA);
  epilogue(oB, lB, qwB);
}

// ---------------------------------------------------------------------------
// Kernel 4: output projection, 128x64 tile (grid 768 = 3/CU even), NEW:
// ring-of-3 staging with counted vmcnt (same T4 pattern as qkv_gemm).
// ---------------------------------------------------------------------------
__global__ __launch_bounds__(256) void out_gemm(
    const bf16* __restrict__ Z, const bf16* __restrict__ WoT,
    const float* __restrict__ bO, float* __restrict__ out) {
  __shared__ bf16 As[3][128 * 32];
  __shared__ bf16 Bs[3][64 * 32];
  const int m0 = blockIdx.x * 128;
  const int n0 = blockIdx.y * 64;
  const int tid = threadIdx.x;
  const int wave = tid >> 6, lane = tid & 63;
  const int quad = lane >> 4, l15 = lane & 15;
  const int wm = (wave & 1) * 64, wn = (wave >> 1) * 32;

  const int r0 = tid >> 2, sg0 = (tid & 3) << 3;
  const int c1 = tid + 256, r1 = c1 >> 2, sg1 = (c1 & 3) << 3;

  auto stage = [&](int k0, int buf) {
    gl2lds16(Z + (size_t)(m0 + r0) * DM + k0 + sg0, &As[buf][tid * 8]);
    gl2lds16(Z + (size_t)(m0 + r1) * DM + k0 + sg1, &As[buf][c1 * 8]);
    gl2lds16(WoT + (size_t)(n0 + r0) * DM + k0 + sg0, &Bs[buf][tid * 8]);
  };

  f32x4 acc[4][2] = {};

  stage(0, 0);   // 3 ops in flight
  stage(32, 1);  // 6
  int cur = 0;
  const int NT = DM / 32;  // 24
  for (int t = 0; t < NT; ++t) {
    if (t + 1 < NT) asm volatile("s_waitcnt vmcnt(3)" ::: "memory");
    else            asm volatile("s_waitcnt vmcnt(0)" ::: "memory");
    __builtin_amdgcn_s_barrier();
    asm volatile("" ::: "memory");
    if (t + 2 < NT) {
      int nxt = cur + 2; if (nxt >= 3) nxt -= 3;
      stage((t + 2) * 32, nxt);
    }
    s16x8 af[4], bfr[2];
    for (int i = 0; i < 4; i++)
      af[i] = *(const s16x8*)&As[cur][(wm + i * 16 + l15) * 32 + quad * 8];
    for (int j = 0; j < 2; j++)
      bfr[j] = *(const s16x8*)&Bs[cur][(wn + j * 16 + l15) * 32 + quad * 8];
    for (int i = 0; i < 4; i++)
      for (int j = 0; j < 2; j++)
        acc[i][j] = MFMA16(af[i], bfr[j], acc[i][j]);
    cur = (cur == 2) ? 0 : cur + 1;
  }

  for (int j = 0; j < 2; j++) {
    int col = n0 + wn + j * 16 + l15;
    float bv = bO[col];
    for (int i = 0; i < 4; i++)
      for (int r = 0; r < 4; r++) {
        int row = m0 + wm + i * 16 + quad * 4 + r;
        out[(size_t)row * DM + col] = acc[i][j][r] + bv;
      }
  }
}

// ---------------------------------------------------------------------------
extern "C" void kernel_launch(void* const* d_in, const int* in_sizes, int n_in,
                              void* d_out, int out_size, void* d_ws,
                              size_t ws_size, hipStream_t stream) {
  const float* x  = (const float*)d_in[0];
  const float* wq = (const float*)d_in[1];
  const float* wk = (const float*)d_in[2];
  const float* wv = (const float*)d_in[3];
  const float* wo = (const float*)d_in[4];
  const float* bq = (const float*)d_in[5];
  const float* bk = (const float*)d_in[6];
  const float* bv = (const float*)d_in[7];
  const float* bo = (const float*)d_in[8];
  float* out = (float*)d_out;

  bf16* WcT = (bf16*)d_ws;                    // 2304*768
  bf16* WoT = WcT + (size_t)QKVC * DM;        //  768*768
  bf16* Qb  = WoT + (size_t)DM * DM;          // 8192*768
  bf16* Kb  = Qb + (size_t)ROWS * DM;         // 8192*768
  bf16* Vt  = Kb + (size_t)ROWS * DM;         // 8192*768 ([bh][h][s])
  bf16* xbZ = Vt + (size_t)ROWS * DM;         // 8192*768 (xb, then Z)

  prep_all<<<NTWC + NTWO + NXB, 256, 0, stream>>>(
      wq, wk, wv, wo, x, WcT, WoT, xbZ);
  qkv_gemm<<<dim3(ROWS / 128, QKVC / 128), 256, 0, stream>>>(
      xbZ, WcT, bq, bk, bv, Qb, Kb, Vt);
  flash_kernel<<<48 * 16, 256, 0, stream>>>(Qb, Kb, Vt, xbZ);
  out_gemm<<<dim3(ROWS / 128, DM / 64), 256, 0, stream>>>(xbZ, WoT, bo, out);
}